// Round 8
// baseline (375.570 us; speedup 1.0000x reference)
//
#include <hip/hip_runtime.h>

// MultiHeadedAttention B=8,S=1024,D=1024,H=16,dk=64 — bf16 MFMA pipeline.
// R12: resubmit of R11 (container-level failure, no pytest output — infra
// suspected). B-direct GEMM: B operand (W, 2MB, L2-resident) loaded straight
// from global per fragment; LDS holds only the A double-buffer (64 KB) with
// the R7-verified XOR swizzle -> 2 blocks/CU (launch_bounds(512,4)), grid
// 768 = exactly 3 blocks/CU. LDS traffic/iter 176->96 KB (R10 post-mortem:
// LDS BW was the bound). Register peak trimmed vs R11 (Wt pointer walk) to
// stay under the 128-VGPR cap (guards the spill-under-graph-capture risk).
// B loads issued BEFORE A staging so counted vmcnt waits only on B.
// R9 attention (exp2-fold, cvt_pk, permlane32_swap, T14) unchanged.

#define Sdim 1024
#define Ddim 1024

typedef unsigned short u16;
typedef float f32x4 __attribute__((ext_vector_type(4)));
typedef float f32x16 __attribute__((ext_vector_type(16)));
typedef __bf16 bf16x8 __attribute__((ext_vector_type(8)));
typedef u16 u16x8 __attribute__((ext_vector_type(8)));
typedef unsigned u32x2 __attribute__((ext_vector_type(2)));
typedef __attribute__((address_space(3))) void lds_void;
typedef __attribute__((address_space(1))) void gbl_void;

__device__ __forceinline__ u16 f2bf(float f) {
    unsigned u = __float_as_uint(f);
    u += 0x7fffu + ((u >> 16) & 1u);   // RNE
    return (u16)(u >> 16);
}
__device__ __forceinline__ void gld16(const void* g, void* l) {
    __builtin_amdgcn_global_load_lds((const gbl_void*)g, (lds_void*)l, 16, 0, 0);
}
__device__ __forceinline__ float fexp2(float x) {
#if __has_builtin(__builtin_amdgcn_exp2f)
    return __builtin_amdgcn_exp2f(x);
#else
    return __expf(x * 0.6931471805599453f);
#endif
}
// pack two f32 -> 2x bf16 (RNE) in one u32: v_cvt_pk_bf16_f32 (no builtin)
__device__ __forceinline__ unsigned cvtpk(float lo, float hi) {
    unsigned r;
    asm("v_cvt_pk_bf16_f32 %0, %1, %2" : "=v"(r) : "v"(lo), "v"(hi));
    return r;
}
#define MFMA16(a, b, c) __builtin_amdgcn_mfma_f32_16x16x32_bf16((a), (b), (c), 0, 0, 0)
#define MFMA32(a, b, c) __builtin_amdgcn_mfma_f32_32x32x16_bf16((a), (b), (c), 0, 0, 0)
#define SCHEDB() __builtin_amdgcn_sched_barrier(0)

#define QSCALE 0.18033688011112042f   // 0.125 * log2(e)

// ---------------------------------------------------------------------------
// fused fp32->bf16 converts; y=0..2 activations (8M), y=3..6 weights (1M).
// y==3 (wq) is scaled by 0.125*log2e (folds 1/sqrt(dk) AND exp->exp2).
// ---------------------------------------------------------------------------
__global__ __launch_bounds__(256) void cvt_all(const float* __restrict__ s0,
                                               const float* __restrict__ s1,
                                               const float* __restrict__ s2,
                                               const float* __restrict__ s3,
                                               const float* __restrict__ s4,
                                               const float* __restrict__ s5,
                                               const float* __restrict__ s6,
                                               u16* __restrict__ d0, u16* __restrict__ d1,
                                               u16* __restrict__ d2, u16* __restrict__ d3,
                                               u16* __restrict__ d4, u16* __restrict__ d5,
                                               u16* __restrict__ d6) {
    const int z = blockIdx.y;
    if (z >= 3 && blockIdx.x >= 512) return;
    const float* s = z == 0 ? s0 : z == 1 ? s1 : z == 2 ? s2 : z == 3 ? s3
                   : z == 4 ? s4 : z == 5 ? s5 : s6;
    u16* d = z == 0 ? d0 : z == 1 ? d1 : z == 2 ? d2 : z == 3 ? d3
           : z == 4 ? d4 : z == 5 ? d5 : d6;
    const float sc = (z == 3) ? QSCALE : 1.0f;
    const int i = (blockIdx.x * 256 + threadIdx.x) * 8;
    const float4 a = *(const float4*)(s + i);
    const float4 b = *(const float4*)(s + i + 4);
    u16x8 o;
    o[0] = f2bf(a.x * sc); o[1] = f2bf(a.y * sc); o[2] = f2bf(a.z * sc); o[3] = f2bf(a.w * sc);
    o[4] = f2bf(b.x * sc); o[5] = f2bf(b.y * sc); o[6] = f2bf(b.z * sc); o[7] = f2bf(b.w * sc);
    *(u16x8*)(d + i) = o;
}

// ---------------------------------------------------------------------------
// B-direct GEMM: C[M][1024] = A[M][1024] @ W[1024][1024]^T + bias*bscale
// Tile 256x128, BK=64, 512 thr = 8 waves (4Mx2N, wave owns 64x64).
// A: LDS dbuf 64KB, XOR swizzle (0 conflicts, verified R7-R10).
// B: direct global loads from L2-resident W; 4 quads of each 16-lane group
// read one contiguous 64B line (coalesced). B loads are issued BEFORE the
// A staging so the compiler's counted vmcnt for the B-frag use leaves the
// 4 A gld16s in flight. 2 blocks/CU gives TLP to hide barrier drains.
// ---------------------------------------------------------------------------
template <bool OUT_BF16>
__device__ __forceinline__ void gemm_bd_body(const u16* __restrict__ A,
                                             const u16* __restrict__ W,
                                             const float* __restrict__ bias, float bscale,
                                             void* __restrict__ Cout,
                                             char* __restrict__ smem,
                                             int m0, int n0) {
    const int tid  = threadIdx.x;
    const int w    = tid >> 6;
    const int lane = tid & 63;
    const int l15  = lane & 15;
    const int quad = lane >> 4;
    const int wr   = w >> 1;          // 0..3 : 64-row block
    const int wc   = w & 1;           // 0..1 : 64-col block

    // A staging: per-lane global src (inverse-swizzled cols), linear LDS dest
    const int lrow = lane >> 3;                       // 0..7
    const int scol = (((lane & 7) ^ lrow) << 3);      // u16 units
    const u16* pa = A + (size_t)(m0 + w * 32 + lrow) * Ddim + scol;
    char* sAw = smem + w * 4096;                      // + buf*32768 + j*1024

#define STG(b)                                                                \
    do {                                                                      \
        gld16(pa,             sAw + (b) * 32768);                             \
        gld16(pa + 8 * 1024,  sAw + (b) * 32768 + 1024);                      \
        gld16(pa + 16 * 1024, sAw + (b) * 32768 + 2048);                      \
        gld16(pa + 24 * 1024, sAw + (b) * 32768 + 3072);                      \
        pa += 64;                                                             \
    } while (0)

    // A fragment read addressing (swizzled)
    const char* Ab = smem + (size_t)(wr * 64 + l15) * 128;
    const int cx = ((quad ^ (l15 & 7)) << 4);

    // B walking pointer: row = n0 + wc*64 + l15 (+j*16), k = quad*8 (+t*64+ks*32)
    const u16* Wt = W + (size_t)(n0 + wc * 64 + l15) * Ddim + quad * 8;

    f32x4 acc[4][4] = {};

    STG(0);   // A tile 0 -> buf0
    __syncthreads();

    for (int t = 0; t < 16; ++t) {
        const int boA = (t & 1) * 32768;
        // B fragments for THIS tile — issued FIRST (oldest in vmem queue)
        bf16x8 bf[2][4];
#pragma unroll
        for (int ks = 0; ks < 2; ++ks)
#pragma unroll
            for (int j = 0; j < 4; ++j)
                bf[ks][j] = *(const bf16x8*)(Wt + (size_t)(j * 16) * Ddim + ks * 32);
        // stage A for next tile (fire-and-forget; drained by the barrier)
        if (t < 15) STG((t & 1) ^ 1);
        SCHEDB();
#pragma unroll
        for (int ks = 0; ks < 2; ++ks) {
            const int cxs = cx ^ (ks << 6);
            bf16x8 af[4];
#pragma unroll
            for (int i = 0; i < 4; ++i)
                af[i] = *(const bf16x8*)(Ab + boA + i * 2048 + cxs);
#pragma unroll
            for (int i = 0; i < 4; ++i)
#pragma unroll
                for (int j = 0; j < 4; ++j)
                    acc[i][j] = MFMA16(af[i], bf[ks][j], acc[i][j]);
        }
        Wt += 64;
        __syncthreads();
    }
#undef STG

    float bv[4];
#pragma unroll
    for (int j = 0; j < 4; ++j)
        bv[j] = bias[n0 + wc * 64 + j * 16 + l15] * bscale;
#pragma unroll
    for (int i = 0; i < 4; ++i)
#pragma unroll
        for (int j = 0; j < 4; ++j)
#pragma unroll
            for (int r = 0; r < 4; ++r) {
                const int row = m0 + wr * 64 + i * 16 + quad * 4 + r;
                const int col = n0 + wc * 64 + j * 16 + l15;
                const float v = acc[i][j][r] + bv[j];
                if (OUT_BF16)
                    ((u16*)Cout)[(size_t)row * Ddim + col] = f2bf(v);
                else
                    ((float*)Cout)[(size_t)row * Ddim + col] = v;
            }
}

__global__ __launch_bounds__(512, 4) void gemm2p_qkv(
        const u16* __restrict__ A0, const u16* __restrict__ A1, const u16* __restrict__ A2,
        const u16* __restrict__ W0, const u16* __restrict__ W1, const u16* __restrict__ W2,
        const float* __restrict__ b0, const float* __restrict__ b1, const float* __restrict__ b2,
        u16* __restrict__ C0, u16* __restrict__ C1, u16* __restrict__ C2) {
    __shared__ __align__(16) char smem[65536];
    const int d = blockIdx.x;                 // 768 WGs, 768 % 8 == 0
    const int s = (d & 7) * 96 + (d >> 3);    // bijective XCD swizzle
    const int z = s >> 8;
    const int rr = s & 255;
    const int tm = rr >> 3, tn = rr & 7;
    const u16* A = z == 0 ? A0 : z == 1 ? A1 : A2;
    const u16* W = z == 0 ? W0 : z == 1 ? W1 : W2;
    const float* bias = z == 0 ? b0 : z == 1 ? b1 : b2;
    u16* C = z == 0 ? C0 : z == 1 ? C1 : C2;
    const float bsc = (z == 0) ? QSCALE : 1.0f;   // wq path is pre-scaled
    gemm_bd_body<true>(A, W, bias, bsc, (void*)C, smem, tm * 256, tn * 128);
}

__global__ __launch_bounds__(512, 4) void gemm2p_dense(const u16* __restrict__ A,
                                                       const u16* __restrict__ W,
                                                       const float* __restrict__ bias,
                                                       float* __restrict__ C) {
    __shared__ __align__(16) char smem[65536];
    const int d = blockIdx.x;                 // 256 WGs
    const int s = (d & 7) * 32 + (d >> 3);
    const int tm = s >> 3, tn = s & 7;
    gemm_bd_body<false>(A, W, bias, 1.0f, (void*)C, smem, tm * 256, tn * 128);
}

// ---------------------------------------------------------------------------
// V transpose: Vp[B*S][D] (bf16) -> Vt_g[(b*16+h)*64 + d][S]
// ---------------------------------------------------------------------------
__global__ __launch_bounds__(256) void transp_v(const u16* __restrict__ Vp,
                                                u16* __restrict__ Vt) {
    __shared__ __align__(16) u16 Ts[64][72];
    const int bh = blockIdx.x, s0 = blockIdx.y * 64;
    const int b = bh >> 4, h = bh & 15;
    const int tid = threadIdx.x;
#pragma unroll
    for (int p = 0; p < 2; ++p) {
        const int e = p * 2048 + tid * 8;
        const int r = e >> 6, c = e & 63;
        *(u16x8*)&Ts[r][c] =
            *(const u16x8*)(Vp + ((size_t)(b * Sdim + s0 + r)) * Ddim + h * 64 + c);
    }
    __syncthreads();
    const int d = tid >> 2, sp = tid & 3;
#pragma unroll
    for (int g = 0; g < 2; ++g) {
        u16x8 o;
#pragma unroll
        for (int j = 0; j < 8; ++j) o[j] = Ts[sp * 16 + g * 8 + j][d];
        *(u16x8*)(Vt + ((size_t)(bh * 64 + d)) * Sdim + s0 + sp * 16 + g * 8) = o;
    }
}

// ---------------------------------------------------------------------------
// Attention on 32x32 MFMA (R9). Grid (128 bh, 4 qblk). Block = 256 q-rows.
// p = exp2(S)*pol (wq pre-scaled 0.125*log2e); C->A via cvt_pk + permlane;
// K/V/pol double-buffered, T14 issue-early/write-late, ONE barrier per kt.
// ---------------------------------------------------------------------------
__global__ __launch_bounds__(256, 2) void attn_mfma(const u16* __restrict__ Qp,
                                                    const u16* __restrict__ Kp,
                                                    const u16* __restrict__ Vt,
                                                    const float* __restrict__ pol,
                                                    u16* __restrict__ Xb) {
    __shared__ __align__(16) u16 lds[37632];    // 75264 B
    u16* Qs = lds;                              // 256 x 72  (later: Xout)
    u16* Ks = lds + 18432;                      // 2 x 64 x 72   K[kpos][dk]
    u16* Vs = lds + 27648;                      // 2 x 64 x 72   V^T[d][kpos]
    float* pols = (float*)(lds + 36864);        // 2 x [64]
    float* denb = pols + 128;                   // [256] inv-den

    const int tid  = threadIdx.x;
    const int w    = tid >> 6;
    const int lane = tid & 63;
    const int l31  = lane & 31;
    const unsigned hsel = lane >> 5;            // half selector
    const int bh = blockIdx.x;
    const int q0 = blockIdx.y * 256;
    const size_t bS = (size_t)(bh >> 4) * Sdim;
    const int col0 = (bh & 15) * 64;
    const int sr = tid >> 2;                    // staging row 0..63
    const int sc4 = tid & 3;                    // staging chunk base

    const u16* Kg = Kp + (bS + sr) * Ddim + col0 + sc4 * 8;
    const u16* Vg = Vt + ((size_t)(bh * 64 + sr)) * Sdim + sc4 * 8;
    const float* pg = pol + bS + tid;

    // ---- stage Q tile 256x64, K/V/pol tile kt=0 into buf0 ----
#pragma unroll
    for (int rg = 0; rg < 4; ++rg) {
        const int r = rg * 64 + sr;
#pragma unroll
        for (int g = 0; g < 2; ++g) {
            const int ch = sc4 + g * 4;
            *(u16x8*)(Qs + r * 72 + ch * 8) =
                *(const u16x8*)(Qp + (bS + q0 + r) * Ddim + col0 + ch * 8);
        }
    }
#pragma unroll
    for (int g = 0; g < 2; ++g) {
        *(u16x8*)(Ks + sr * 72 + (sc4 + g * 4) * 8) = *(const u16x8*)(Kg + g * 32);
        *(u16x8*)(Vs + sr * 72 + (sc4 + g * 4) * 8) = *(const u16x8*)(Vg + g * 32);
    }
    if (tid < 64) pols[tid] = pg[0];
    __syncthreads();

    bf16x8 Qf[2][4];
#pragma unroll
    for (int qt = 0; qt < 2; ++qt)
#pragma unroll
        for (int dkt = 0; dkt < 4; ++dkt)
            Qf[qt][dkt] = *(const bf16x8*)(Qs + (w * 64 + qt * 32 + l31) * 72 +
                                           dkt * 16 + hsel * 8);

    f32x16 X[2][2] = {};
    float den[2] = {0.f, 0.f};

    for (int kt = 0; kt < 16; ++kt) {
        const int cur = kt & 1;
        const bool pf = (kt < 15);
        // ---- T14 issue-early: next tile's global loads into regs ----
        u16x8 kr0 = {}, kr1 = {}, vr0 = {}, vr1 = {};
        float polr = 0.f;
        if (pf) {
            const int ko = (kt + 1) * 64;
            kr0 = *(const u16x8*)(Kg + (size_t)ko * Ddim);
            kr1 = *(const u16x8*)(Kg + (size_t)ko * Ddim + 32);
            vr0 = *(const u16x8*)(Vg + ko);
            vr1 = *(const u16x8*)(Vg + ko + 32);
            if (tid < 64) polr = pg[ko];
        }
        SCHEDB();   // keep load issue above compute

        const u16* Ksc = Ks + cur * 4608;
        const u16* Vsc = Vs + cur * 4608;
        const float* polc = pols + cur * 64;
#pragma unroll
        for (int t32 = 0; t32 < 2; ++t32) {
            float polv[16];
#pragma unroll
            for (int e = 0; e < 16; ++e)
                polv[e] = polc[t32 * 32 + (e & 3) + 8 * (e >> 2) + 4 * hsel];
            bf16x8 Kf[4];
#pragma unroll
            for (int dkt = 0; dkt < 4; ++dkt)
                Kf[dkt] = *(const bf16x8*)(Ksc + (t32 * 32 + l31) * 72 +
                                           dkt * 16 + hsel * 8);
#pragma unroll
            for (int qt = 0; qt < 2; ++qt) {
                f32x16 S = {};
#pragma unroll
                for (int dkt = 0; dkt < 4; ++dkt)
                    S = MFMA32(Kf[dkt], Qf[qt][dkt], S);   // D[kpos][q]
                float p[16];
#pragma unroll
                for (int e = 0; e < 16; ++e) {
                    p[e] = fexp2(S[e]) * polv[e];
                    den[qt] += p[e];
                }
                unsigned pk_[8];
#pragma unroll
                for (int g = 0; g < 4; ++g) {
                    pk_[2 * g]     = cvtpk(p[4 * g + 0], p[4 * g + 1]);
                    pk_[2 * g + 1] = cvtpk(p[4 * g + 2], p[4 * g + 3]);
                }
#pragma unroll
                for (int tau = 0; tau < 2; ++tau) {
                    const u32x2 sA = __builtin_amdgcn_permlane32_swap(
                        pk_[4 * tau + 0], pk_[4 * tau + 2], false, false);
                    const u32x2 sB = __builtin_amdgcn_permlane32_swap(
                        pk_[4 * tau + 1], pk_[4 * tau + 3], false, false);
                    union { unsigned u[4]; bf16x8 v; } Af;
                    Af.u[0] = sA[0]; Af.u[1] = sB[0];
                    Af.u[2] = sA[1]; Af.u[3] = sB[1];
#pragma unroll
                    for (int ndt = 0; ndt < 2; ++ndt) {
                        const bf16x8 Vf =
                            *(const bf16x8*)(Vsc + (ndt * 32 + l31) * 72 +
                                             t32 * 32 + tau * 16 + hsel * 8);
                        X[qt][ndt] = MFMA32(Af.v, Vf, X[qt][ndt]);  // D[q][d]
                    }
                }
            }
        }
        // ---- T14 write-late: publish next tile into the other buffer ----
        if (pf) {
            const int nxt = cur ^ 1;
            *(u16x8*)(Ks + nxt * 4608 + sr * 72 + sc4 * 8) = kr0;
            *(u16x8*)(Ks + nxt * 4608 + sr * 72 + (sc4 + 4) * 8) = kr1;
            *(u16x8*)(Vs + nxt * 4608 + sr * 72 + sc4 * 8) = vr0;
            *(u16x8*)(Vs + nxt * 4608 + sr * 72 + (sc4 + 4) * 8) = vr1;
            if (tid < 64) pols[nxt * 64 + tid] = polr;
        }
        __syncthreads();
    }

    // ---- epilogue: den reduce, normalize, stage to LDS, coalesced store ----
#pragma unroll
    for (int qt = 0; qt < 2; ++qt) {
        den[qt] += __shfl_xor(den[qt], 32);
        denb[w * 64 + qt * 32 + l31] = 1.0f / (den[qt] + 1e-6f);
    }
    u16* Xout = Qs;   // Q frags live in regs; Qs region reused (barriers below)
#pragma unroll
    for (int qt = 0; qt < 2; ++qt) {
        float invv[16];
#pragma unroll
        for (int e = 0; e < 16; ++e)
            invv[e] = denb[w * 64 + qt * 32 + (e & 3) + 8 * (e >> 2) + 4 * hsel];
#pragma unroll
        for (int ndt = 0; ndt < 2; ++ndt)
#pragma unroll
            for (int e = 0; e < 16; ++e) {
                const int rho = (e & 3) + 8 * (e >> 2) + 4 * hsel;
                Xout[(w * 64 + qt * 32 + rho) * 72 + ndt * 32 + l31] =
                    f2bf(X[qt][ndt][e] * invv[e]);
            }
    }
    __syncthreads();
#pragma unroll
    for (int rg = 0; rg < 4; ++rg) {
        const int r = rg * 64 + sr;
#pragma unroll
        for (int g = 0; g < 2; ++g) {
            const int ch = sc4 + g * 4;
            *(u16x8*)(Xb + (bS + q0 + r) * Ddim + col0 + ch * 8) =
                *(const u16x8*)(Xout + r * 72 + ch * 8);
        }
    }
}

// ---------------------------------------------------------------------------
extern "C" void kernel_launch(void* const* d_in, const int* in_sizes, int n_in,
                              void* d_out, int out_size, void* d_ws, size_t ws_size,
                              hipStream_t stream) {
    const float* query   = (const float*)d_in[0];
    const float* key     = (const float*)d_in[1];
    const float* value   = (const float*)d_in[2];
    const float* policy  = (const float*)d_in[3];
    const float* wq_w    = (const float*)d_in[4];
    const float* wq_b    = (const float*)d_in[5];
    const float* wk_w    = (const float*)d_in[6];
    const float* wk_b    = (const float*)d_in[7];
    const float* wv_w    = (const float*)d_in[8];
    const float* wv_b    = (const float*)d_in[9];
    const float* dense_w = (const float*)d_in[10];
    const float* dense_b = (const float*)d_in[11];

    const size_t MM = 1u << 20;
    const size_t A8 = 8 * MM;
    u16* qa  = (u16*)d_ws;        // later aliased as Xb
    u16* ka  = qa + A8;           // later aliased as Vtg
    u16* va  = ka + A8;
    u16* wqb = va + A8;
    u16* wkb = wqb + MM;
    u16* wvb = wkb + MM;
    u16* wdb = wvb + MM;
    u16* Qp  = wdb + MM;
    u16* Kp  = Qp + A8;
    u16* Vp  = Kp + A8;
    u16* Vtg = ka;                // safe: ka consumed by gemm2p_qkv before transp_v
    u16* Xb  = qa;                // safe: qa consumed by gemm2p_qkv before attn

    cvt_all<<<dim3(4096, 7), 256, 0, stream>>>(query, key, value, wq_w, wk_w, wv_w, dense_w,
                                               qa, ka, va, wqb, wkb, wvb, wdb);

    gemm2p_qkv<<<dim3(768), 512, 0, stream>>>(qa, ka, va, wqb, wkb, wvb,
                                              wq_b, wk_b, wv_b, Qp, Kp, Vp);
    transp_v<<<dim3(128, 16), 256, 0, stream>>>(Vp, Vtg);

    attn_mfma<<<dim3(128, 4), 256, 0, stream>>>(Qp, Kp, Vtg, policy, Xb);

    gemm2p_dense<<<dim3(256), 512, 0, stream>>>(Xb, wdb, dense_b, (float*)d_out);
}

// Round 10
// 292.321 us; speedup vs baseline: 1.2848x; 1.2848x over previous
//
#include <hip/hip_runtime.h>

// MultiHeadedAttention B=8,S=1024,D=1024,H=16,dk=64 — bf16 MFMA pipeline.
// R14: resubmit of R13 (container-level failure, no pytest output; full
// audit of the new V-epilogue found no OOB/barrier/bank fault — infra
// suspected, matching the R5->R6 and R11->R12 pattern).
// Design: R9-proven 2-phase GEMMs (60us QKV ~ 858TF); transp_v retired —
// the V-GEMM (z==2) epilogue transposes its 256x128 tile through the
// dead-at-epilogue staging LDS (stride 133 u16, <=2-way banks both phases)
// and stores straight in Vt layout [(b*16+h)*64+d][s]. Saves one launch,
// ~8us, and 32MB HBM. R9 attention unchanged. 4 launches total.

#define Sdim 1024
#define Ddim 1024

typedef unsigned short u16;
typedef float f32x4 __attribute__((ext_vector_type(4)));
typedef float f32x16 __attribute__((ext_vector_type(16)));
typedef __bf16 bf16x8 __attribute__((ext_vector_type(8)));
typedef u16 u16x8 __attribute__((ext_vector_type(8)));
typedef unsigned u32x2 __attribute__((ext_vector_type(2)));
typedef __attribute__((address_space(3))) void lds_void;
typedef __attribute__((address_space(1))) void gbl_void;

__device__ __forceinline__ u16 f2bf(float f) {
    unsigned u = __float_as_uint(f);
    u += 0x7fffu + ((u >> 16) & 1u);   // RNE
    return (u16)(u >> 16);
}
__device__ __forceinline__ void gld16(const void* g, void* l) {
    __builtin_amdgcn_global_load_lds((const gbl_void*)g, (lds_void*)l, 16, 0, 0);
}
__device__ __forceinline__ float fexp2(float x) {
#if __has_builtin(__builtin_amdgcn_exp2f)
    return __builtin_amdgcn_exp2f(x);
#else
    return __expf(x * 0.6931471805599453f);
#endif
}
// pack two f32 -> 2x bf16 (RNE) in one u32: v_cvt_pk_bf16_f32 (no builtin)
__device__ __forceinline__ unsigned cvtpk(float lo, float hi) {
    unsigned r;
    asm("v_cvt_pk_bf16_f32 %0, %1, %2" : "=v"(r) : "v"(lo), "v"(hi));
    return r;
}
#define MFMA16(a, b, c) __builtin_amdgcn_mfma_f32_16x16x32_bf16((a), (b), (c), 0, 0, 0)
#define MFMA32(a, b, c) __builtin_amdgcn_mfma_f32_32x32x16_bf16((a), (b), (c), 0, 0, 0)
#define SCHEDB() __builtin_amdgcn_sched_barrier(0)

#define QSCALE 0.18033688011112042f   // 0.125 * log2(e)

// ---------------------------------------------------------------------------
// fused fp32->bf16 converts; y=0..2 activations (8M), y=3..6 weights (1M).
// y==3 (wq) is scaled by 0.125*log2e (folds 1/sqrt(dk) AND exp->exp2).
// ---------------------------------------------------------------------------
__global__ __launch_bounds__(256) void cvt_all(const float* __restrict__ s0,
                                               const float* __restrict__ s1,
                                               const float* __restrict__ s2,
                                               const float* __restrict__ s3,
                                               const float* __restrict__ s4,
                                               const float* __restrict__ s5,
                                               const float* __restrict__ s6,
                                               u16* __restrict__ d0, u16* __restrict__ d1,
                                               u16* __restrict__ d2, u16* __restrict__ d3,
                                               u16* __restrict__ d4, u16* __restrict__ d5,
                                               u16* __restrict__ d6) {
    const int z = blockIdx.y;
    if (z >= 3 && blockIdx.x >= 512) return;
    const float* s = z == 0 ? s0 : z == 1 ? s1 : z == 2 ? s2 : z == 3 ? s3
                   : z == 4 ? s4 : z == 5 ? s5 : s6;
    u16* d = z == 0 ? d0 : z == 1 ? d1 : z == 2 ? d2 : z == 3 ? d3
           : z == 4 ? d4 : z == 5 ? d5 : d6;
    const float sc = (z == 3) ? QSCALE : 1.0f;
    const int i = (blockIdx.x * 256 + threadIdx.x) * 8;
    const float4 a = *(const float4*)(s + i);
    const float4 b = *(const float4*)(s + i + 4);
    u16x8 o;
    o[0] = f2bf(a.x * sc); o[1] = f2bf(a.y * sc); o[2] = f2bf(a.z * sc); o[3] = f2bf(a.w * sc);
    o[4] = f2bf(b.x * sc); o[5] = f2bf(b.y * sc); o[6] = f2bf(b.z * sc); o[7] = f2bf(b.w * sc);
    *(u16x8*)(d + i) = o;
}

// ---------------------------------------------------------------------------
// 2-phase GEMM (R9-proven loop): C = A @ W^T + bias*bscale
// Tile 256x128, BK=64, 512 thr = 8 waves (4Mx2N, wave owns 64x64).
// LDS 96KB: As[2][256][64] @0, Bs[2][128][64] @65536; XOR chunk swizzle
// (0 conflicts, verified R7-R10). Per tile: {STG(t+1); compute; barrier}.
// OM: 0 = f32 C, 1 = bf16 C, 2 = bf16 transposed to Vt[(b*16+h)*64+d][s]
// (epilogue LDS transpose, stride 133 u16 — both phases <=2-way on banks).
// ---------------------------------------------------------------------------
template <int OM>
__device__ __forceinline__ void gemm2p_body(const u16* __restrict__ A,
                                            const u16* __restrict__ W,
                                            const float* __restrict__ bias, float bscale,
                                            void* __restrict__ Cout,
                                            char* __restrict__ smem,
                                            int m0, int n0) {
    const int tid  = threadIdx.x;
    const int w    = tid >> 6;
    const int lane = tid & 63;
    const int l15  = lane & 15;
    const int quad = lane >> 4;
    const int wr   = w >> 1;          // 0..3 : 64-row block
    const int wc   = w & 1;           // 0..1 : 64-col block

    const int lrow = lane >> 3;                       // 0..7
    const int scol = (((lane & 7) ^ lrow) << 3);      // u16 units
    const u16* pa = A + (size_t)(m0 + w * 32 + lrow) * Ddim + scol;
    const u16* pb = W + (size_t)(n0 + w * 16 + lrow) * Ddim + scol;
    char* sAw = smem + w * 4096;
    char* sBw = smem + 65536 + w * 2048;

#define STG(t, b)                                                             \
    do {                                                                      \
        const int k0 = (t) * 64;                                              \
        gld16(pa + k0,             sAw + (b) * 32768);                        \
        gld16(pa + k0 + 8 * 1024,  sAw + (b) * 32768 + 1024);                 \
        gld16(pa + k0 + 16 * 1024, sAw + (b) * 32768 + 2048);                 \
        gld16(pa + k0 + 24 * 1024, sAw + (b) * 32768 + 3072);                 \
        gld16(pb + k0,             sBw + (b) * 16384);                        \
        gld16(pb + k0 + 8 * 1024,  sBw + (b) * 16384 + 1024);                 \
    } while (0)

    const char* Ab = smem + (size_t)(wr * 64 + l15) * 128;
    const char* Bb = smem + 65536 + (size_t)(wc * 64 + l15) * 128;
    const int cx = ((quad ^ (l15 & 7)) << 4);

    f32x4 acc[4][4] = {};

    STG(0, 0);
    __syncthreads();

    for (int t = 0; t < 16; ++t) {
        const int boA = (t & 1) * 32768;
        const int boB = (t & 1) * 16384;
        if (t < 15) STG(t + 1, (t & 1) ^ 1);
        SCHEDB();
#pragma unroll
        for (int ks = 0; ks < 2; ++ks) {
            const int cxs = cx ^ (ks << 6);
            bf16x8 af[4], bfr[4];
#pragma unroll
            for (int i = 0; i < 4; ++i)
                af[i] = *(const bf16x8*)(Ab + boA + i * 2048 + cxs);
#pragma unroll
            for (int j = 0; j < 4; ++j)
                bfr[j] = *(const bf16x8*)(Bb + boB + j * 2048 + cxs);
#pragma unroll
            for (int i = 0; i < 4; ++i)
#pragma unroll
                for (int j = 0; j < 4; ++j)
                    acc[i][j] = MFMA16(af[i], bfr[j], acc[i][j]);
        }
        __syncthreads();
    }
#undef STG

    float bv[4];
#pragma unroll
    for (int j = 0; j < 4; ++j)
        bv[j] = bias[n0 + wc * 64 + j * 16 + l15] * bscale;

    if (OM == 2) {
        // ---- V epilogue: LDS transpose -> Vt[(b*16+h)*64+d][s] ----
        u16* Ts = (u16*)smem;   // 256 x 133 u16 = 68096 B (staging is dead)
#pragma unroll
        for (int i = 0; i < 4; ++i)
#pragma unroll
            for (int j = 0; j < 4; ++j)
#pragma unroll
                for (int r = 0; r < 4; ++r)
                    Ts[(wr * 64 + i * 16 + quad * 4 + r) * 133 +
                       wc * 64 + j * 16 + l15] = f2bf(acc[i][j][r] + bv[j]);
        __syncthreads();
        const int dcol = tid >> 2;           // 0..127
        const int sp   = tid & 3;
        const int b    = m0 >> 10;
        const int sb0  = m0 & 1023;
        const int h    = (n0 >> 6) + (dcol >> 6);
        const int dd   = dcol & 63;
        u16* vrow = (u16*)Cout + ((size_t)((b << 4) + h) * 64 + dd) * Sdim + sb0;
#pragma unroll
        for (int sblk = 0; sblk < 4; ++sblk)
#pragma unroll
            for (int g = 0; g < 2; ++g) {
                const int c = sblk * 64 + sp * 16 + g * 8;
                u16x8 o;
#pragma unroll
                for (int e = 0; e < 8; ++e) o[e] = Ts[(c + e) * 133 + dcol];
                *(u16x8*)(vrow + c) = o;
            }
    } else {
#pragma unroll
        for (int i = 0; i < 4; ++i)
#pragma unroll
            for (int j = 0; j < 4; ++j)
#pragma unroll
                for (int r = 0; r < 4; ++r) {
                    const int row = m0 + wr * 64 + i * 16 + quad * 4 + r;
                    const int col = n0 + wc * 64 + j * 16 + l15;
                    const float v = acc[i][j][r] + bv[j];
                    if (OM == 1)
                        ((u16*)Cout)[(size_t)row * Ddim + col] = f2bf(v);
                    else
                        ((float*)Cout)[(size_t)row * Ddim + col] = v;
                }
    }
}

__global__ __launch_bounds__(512, 2) void gemm2p_qkv(
        const u16* __restrict__ A0, const u16* __restrict__ A1, const u16* __restrict__ A2,
        const u16* __restrict__ W0, const u16* __restrict__ W1, const u16* __restrict__ W2,
        const float* __restrict__ b0, const float* __restrict__ b1, const float* __restrict__ b2,
        u16* __restrict__ C0, u16* __restrict__ C1, u16* __restrict__ C2) {
    __shared__ __align__(16) char smem[98304];
    const int d = blockIdx.x;                 // 768 WGs, 768 % 8 == 0
    const int s = (d & 7) * 96 + (d >> 3);    // bijective XCD swizzle
    const int z = s >> 8;
    const int rr = s & 255;
    const int tm = rr >> 3, tn = rr & 7;
    const u16* A = z == 0 ? A0 : z == 1 ? A1 : A2;
    const u16* W = z == 0 ? W0 : z == 1 ? W1 : W2;
    const float* bias = z == 0 ? b0 : z == 1 ? b1 : b2;
    u16* C = z == 0 ? C0 : z == 1 ? C1 : C2;
    const float bsc = (z == 0) ? QSCALE : 1.0f;   // wq path is pre-scaled
    if (z == 2)
        gemm2p_body<2>(A, W, bias, bsc, (void*)C, smem, tm * 256, tn * 128);
    else
        gemm2p_body<1>(A, W, bias, bsc, (void*)C, smem, tm * 256, tn * 128);
}

__global__ __launch_bounds__(512, 2) void gemm2p_dense(const u16* __restrict__ A,
                                                       const u16* __restrict__ W,
                                                       const float* __restrict__ bias,
                                                       float* __restrict__ C) {
    __shared__ __align__(16) char smem[98304];
    const int d = blockIdx.x;                 // 256 WGs
    const int s = (d & 7) * 32 + (d >> 3);
    const int tm = s >> 3, tn = s & 7;
    gemm2p_body<0>(A, W, bias, 1.0f, (void*)C, smem, tm * 256, tn * 128);
}

// ---------------------------------------------------------------------------
// Attention on 32x32 MFMA (R9). Grid (128 bh, 4 qblk). Block = 256 q-rows.
// p = exp2(S)*pol (wq pre-scaled 0.125*log2e); C->A via cvt_pk + permlane;
// K/V/pol double-buffered, T14 issue-early/write-late, ONE barrier per kt.
// Vt comes straight from the V-GEMM epilogue (layout [(b*16+h)*64+d][s]).
// ---------------------------------------------------------------------------
__global__ __launch_bounds__(256, 2) void attn_mfma(const u16* __restrict__ Qp,
                                                    const u16* __restrict__ Kp,
                                                    const u16* __restrict__ Vt,
                                                    const float* __restrict__ pol,
                                                    u16* __restrict__ Xb) {
    __shared__ __align__(16) u16 lds[37632];    // 75264 B
    u16* Qs = lds;                              // 256 x 72  (later: Xout)
    u16* Ks = lds + 18432;                      // 2 x 64 x 72   K[kpos][dk]
    u16* Vs = lds + 27648;                      // 2 x 64 x 72   V^T[d][kpos]
    float* pols = (float*)(lds + 36864);        // 2 x [64]
    float* denb = pols + 128;                   // [256] inv-den

    const int tid  = threadIdx.x;
    const int w    = tid >> 6;
    const int lane = tid & 63;
    const int l31  = lane & 31;
    const unsigned hsel = lane >> 5;            // half selector
    const int bh = blockIdx.x;
    const int q0 = blockIdx.y * 256;
    const size_t bS = (size_t)(bh >> 4) * Sdim;
    const int col0 = (bh & 15) * 64;
    const int sr = tid >> 2;                    // staging row 0..63
    const int sc4 = tid & 3;                    // staging chunk base

    const u16* Kg = Kp + (bS + sr) * Ddim + col0 + sc4 * 8;
    const u16* Vg = Vt + ((size_t)(bh * 64 + sr)) * Sdim + sc4 * 8;
    const float* pg = pol + bS + tid;

    // ---- stage Q tile 256x64, K/V/pol tile kt=0 into buf0 ----
#pragma unroll
    for (int rg = 0; rg < 4; ++rg) {
        const int r = rg * 64 + sr;
#pragma unroll
        for (int g = 0; g < 2; ++g) {
            const int ch = sc4 + g * 4;
            *(u16x8*)(Qs + r * 72 + ch * 8) =
                *(const u16x8*)(Qp + (bS + q0 + r) * Ddim + col0 + ch * 8);
        }
    }
#pragma unroll
    for (int g = 0; g < 2; ++g) {
        *(u16x8*)(Ks + sr * 72 + (sc4 + g * 4) * 8) = *(const u16x8*)(Kg + g * 32);
        *(u16x8*)(Vs + sr * 72 + (sc4 + g * 4) * 8) = *(const u16x8*)(Vg + g * 32);
    }
    if (tid < 64) pols[tid] = pg[0];
    __syncthreads();

    bf16x8 Qf[2][4];
#pragma unroll
    for (int qt = 0; qt < 2; ++qt)
#pragma unroll
        for (int dkt = 0; dkt < 4; ++dkt)
            Qf[qt][dkt] = *(const bf16x8*)(Qs + (w * 64 + qt * 32 + l31) * 72 +
                                           dkt * 16 + hsel * 8);

    f32x16 X[2][2] = {};
    float den[2] = {0.f, 0.f};

    for (int kt = 0; kt < 16; ++kt) {
        const int cur = kt & 1;
        const bool pf = (kt < 15);
        // ---- T14 issue-early: next tile's global loads into regs ----
        u16x8 kr0 = {}, kr1 = {}, vr0 = {}, vr1 = {};
        float polr = 0.f;
        if (pf) {
            const int ko = (kt + 1) * 64;
            kr0 = *(const u16x8*)(Kg + (size_t)ko * Ddim);
            kr1 = *(const u16x8*)(Kg + (size_t)ko * Ddim + 32);
            vr0 = *(const u16x8*)(Vg + ko);
            vr1 = *(const u16x8*)(Vg + ko + 32);
            if (tid < 64) polr = pg[ko];
        }
        SCHEDB();   // keep load issue above compute

        const u16* Ksc = Ks + cur * 4608;
        const u16* Vsc = Vs + cur * 4608;
        const float* polc = pols + cur * 64;
#pragma unroll
        for (int t32 = 0; t32 < 2; ++t32) {
            float polv[16];
#pragma unroll
            for (int e = 0; e < 16; ++e)
                polv[e] = polc[t32 * 32 + (e & 3) + 8 * (e >> 2) + 4 * hsel];
            bf16x8 Kf[4];
#pragma unroll
            for (int dkt = 0; dkt < 4; ++dkt)
                Kf[dkt] = *(const bf16x8*)(Ksc + (t32 * 32 + l31) * 72 +
                                           dkt * 16 + hsel * 8);
#pragma unroll
            for (int qt = 0; qt < 2; ++qt) {
                f32x16 S = {};
#pragma unroll
                for (int dkt = 0; dkt < 4; ++dkt)
                    S = MFMA32(Kf[dkt], Qf[qt][dkt], S);   // D[kpos][q]
                float p[16];
#pragma unroll
                for (int e = 0; e < 16; ++e) {
                    p[e] = fexp2(S[e]) * polv[e];
                    den[qt] += p[e];
                }
                unsigned pk_[8];
#pragma unroll
                for (int g = 0; g < 4; ++g) {
                    pk_[2 * g]     = cvtpk(p[4 * g + 0], p[4 * g + 1]);
                    pk_[2 * g + 1] = cvtpk(p[4 * g + 2], p[4 * g + 3]);
                }
#pragma unroll
                for (int tau = 0; tau < 2; ++tau) {
                    const u32x2 sA = __builtin_amdgcn_permlane32_swap(
                        pk_[4 * tau + 0], pk_[4 * tau + 2], false, false);
                    const u32x2 sB = __builtin_amdgcn_permlane32_swap(
                        pk_[4 * tau + 1], pk_[4 * tau + 3], false, false);
                    union { unsigned u[4]; bf16x8 v; } Af;
                    Af.u[0] = sA[0]; Af.u[1] = sB[0];
                    Af.u[2] = sA[1]; Af.u[3] = sB[1];
#pragma unroll
                    for (int ndt = 0; ndt < 2; ++ndt) {
                        const bf16x8 Vf =
                            *(const bf16x8*)(Vsc + (ndt * 32 + l31) * 72 +
                                             t32 * 32 + tau * 16 + hsel * 8);
                        X[qt][ndt] = MFMA32(Af.v, Vf, X[qt][ndt]);  // D[q][d]
                    }
                }
            }
        }
        // ---- T14 write-late: publish next tile into the other buffer ----
        if (pf) {
            const int nxt = cur ^ 1;
            *(u16x8*)(Ks + nxt * 4608 + sr * 72 + sc4 * 8) = kr0;
            *(u16x8*)(Ks + nxt * 4608 + sr * 72 + (sc4 + 4) * 8) = kr1;
            *(u16x8*)(Vs + nxt * 4608 + sr * 72 + sc4 * 8) = vr0;
            *(u16x8*)(Vs + nxt * 4608 + sr * 72 + (sc4 + 4) * 8) = vr1;
            if (tid < 64) pols[nxt * 64 + tid] = polr;
        }
        __syncthreads();
    }

    // ---- epilogue: den reduce, normalize, stage to LDS, coalesced store ----
#pragma unroll
    for (int qt = 0; qt < 2; ++qt) {
        den[qt] += __shfl_xor(den[qt], 32);
        denb[w * 64 + qt * 32 + l31] = 1.0f / (den[qt] + 1e-6f);
    }
    u16* Xout = Qs;   // Q frags live in regs; Qs region reused (barriers below)
#pragma unroll
    for (int qt = 0; qt < 2; ++qt) {
        float invv[16];
#pragma unroll
        for (int e = 0; e < 16; ++e)
            invv[e] = denb[w * 64 + qt * 32 + (e & 3) + 8 * (e >> 2) + 4 * hsel];
#pragma unroll
        for (int ndt = 0; ndt < 2; ++ndt)
#pragma unroll
            for (int e = 0; e < 16; ++e) {
                const int rho = (e & 3) + 8 * (e >> 2) + 4 * hsel;
                Xout[(w * 64 + qt * 32 + rho) * 72 + ndt * 32 + l31] =
                    f2bf(X[qt][ndt][e] * invv[e]);
            }
    }
    __syncthreads();
#pragma unroll
    for (int rg = 0; rg < 4; ++rg) {
        const int r = rg * 64 + sr;
#pragma unroll
        for (int g = 0; g < 2; ++g) {
            const int ch = sc4 + g * 4;
            *(u16x8*)(Xb + (bS + q0 + r) * Ddim + col0 + ch * 8) =
                *(const u16x8*)(Xout + r * 72 + ch * 8);
        }
    }
}

// ---------------------------------------------------------------------------
extern "C" void kernel_launch(void* const* d_in, const int* in_sizes, int n_in,
                              void* d_out, int out_size, void* d_ws, size_t ws_size,
                              hipStream_t stream) {
    const float* query   = (const float*)d_in[0];
    const float* key     = (const float*)d_in[1];
    const float* value   = (const float*)d_in[2];
    const float* policy  = (const float*)d_in[3];
    const float* wq_w    = (const float*)d_in[4];
    const float* wq_b    = (const float*)d_in[5];
    const float* wk_w    = (const float*)d_in[6];
    const float* wk_b    = (const float*)d_in[7];
    const float* wv_w    = (const float*)d_in[8];
    const float* wv_b    = (const float*)d_in[9];
    const float* dense_w = (const float*)d_in[10];
    const float* dense_b = (const float*)d_in[11];

    const size_t MM = 1u << 20;
    const size_t A8 = 8 * MM;
    u16* qa  = (u16*)d_ws;        // later aliased as Xb
    u16* ka  = qa + A8;
    u16* va  = ka + A8;
    u16* wqb = va + A8;
    u16* wkb = wqb + MM;
    u16* wvb = wkb + MM;
    u16* wdb = wvb + MM;
    u16* Qp  = wdb + MM;
    u16* Kp  = Qp + A8;
    u16* Vt  = Kp + A8;           // V-GEMM writes Vt layout here directly
    u16* Xb  = qa;                // safe: qa consumed by gemm2p_qkv before attn

    cvt_all<<<dim3(4096, 7), 256, 0, stream>>>(query, key, value, wq_w, wk_w, wv_w, dense_w,
                                               qa, ka, va, wqb, wkb, wvb, wdb);

    gemm2p_qkv<<<dim3(768), 512, 0, stream>>>(qa, ka, va, wqb, wkb, wvb,
                                              wq_b, wk_b, wv_b, Qp, Kp, Vt);

    attn_mfma<<<dim3(128, 4), 256, 0, stream>>>(Qp, Kp, Vt, policy, Xb);

    gemm2p_dense<<<dim3(256), 512, 0, stream>>>(Xb, wdb, dense_b, (float*)d_out);
}